// Round 5
// baseline (175.841 us; speedup 1.0000x reference)
//
#include <hip/hip_runtime.h>
#include <math.h>

// Problem constants (fixed by setup_inputs): B=8, N=M=8192, D=3, fp32.
#define BB 8
#define NN 8192
#define MM 8192
#define BN (BB * NN)   // 65536 pred points
#define BM (BB * MM)   // 65536 tgt points
#define NPAIR (BN / 2) // 32768 point-pairs per side

#define BLOCK 256
#define RROWS 8                    // query rows per thread
#define QB (BLOCK * RROWS)         // 2048 queries per block
#define SPLIT 64                   // m-dimension split across blocks

#define INF_KEY 0x7F7F7F7F         // decodes to a huge positive float

typedef float v2f __attribute__((ext_vector_type(2)));
typedef float v4f __attribute__((ext_vector_type(4)));

// Monotone float->int key so signed-int atomicMin orders like float.
__device__ __forceinline__ int enc_key(float v) {
    int b = __float_as_int(v);
    return b >= 0 ? b : (b ^ 0x7fffffff);
}
__device__ __forceinline__ float dec_key(int k) {
    int b = k >= 0 ? k : (k ^ 0x7fffffff);
    return __int_as_float(b);
}

// Pack points into PAIR-SoA layout: pair j = points 2j,2j+1 stored as two
// float4s: [x0 x1 y0 y1] [z0 z1 w0 w1], w = |p|^2. This layout delivers the
// v_pk_fma_f32 source pairs directly from global_load_dwordx4 (even-aligned
// register pairs, zero shuffle movs). Also inits min-keys, zeroes out.
__global__ __launch_bounds__(BLOCK) void chamfer_pack(
        const float* __restrict__ pred, const float* __restrict__ tgt,
        float4* __restrict__ pp, float4* __restrict__ pt,
        int* __restrict__ rk, int* __restrict__ ck,
        float* __restrict__ out) {
    int j = blockIdx.x * BLOCK + threadIdx.x;      // pair index
    {
        const float* p = pred + (size_t)j * 6;
        float x0 = p[0], y0 = p[1], z0 = p[2], x1 = p[3], y1 = p[4], z1 = p[5];
        float w0 = fmaf(x0, x0, fmaf(y0, y0, z0 * z0));
        float w1 = fmaf(x1, x1, fmaf(y1, y1, z1 * z1));
        pp[j * 2 + 0] = make_float4(x0, x1, y0, y1);
        pp[j * 2 + 1] = make_float4(z0, z1, w0, w1);
    }
    {
        const float* p = tgt + (size_t)j * 6;
        float x0 = p[0], y0 = p[1], z0 = p[2], x1 = p[3], y1 = p[4], z1 = p[5];
        float w0 = fmaf(x0, x0, fmaf(y0, y0, z0 * z0));
        float w1 = fmaf(x1, x1, fmaf(y1, y1, z1 * z1));
        pt[j * 2 + 0] = make_float4(x0, x1, y0, y1);
        pt[j * 2 + 1] = make_float4(z0, z1, w0, w1);
    }
    ((int2*)rk)[j] = make_int2(INF_KEY, INF_KEY);
    ((int2*)ck)[j] = make_int2(INF_KEY, INF_KEY);
    if (blockIdx.x == 0 && threadIdx.x < BB) out[threadIdx.x] = 0.0f;
}

// Both chamfer directions in one dispatch (blockIdx.z). Each thread owns 8
// query rows; streams target PAIRS. Inner body per (row, target-pair):
// 3 v_pk_fma_f32 (forced via inline asm so instcombine can't scalarize the
// uniform broadcasts) + 1 v_min3_f32 = 4 issue slots for 2 point-pairs.
__global__ __launch_bounds__(BLOCK) void chamfer_minpass(
        const float4* __restrict__ pp, const float4* __restrict__ pt,
        int* __restrict__ rk, int* __restrict__ ck) {
    const bool second = (blockIdx.z != 0);
    const float4* __restrict__ qry = second ? pt : pp;
    const float4* __restrict__ tgt = second ? pp : pt;
    int* __restrict__ okeys = second ? ck : rk;

    const int qbase = blockIdx.x * QB;
    const int b = qbase / NN;              // QB | NN: block never straddles a batch
    const int t = threadIdx.x;

    v2f nxp[RROWS], nyp[RROWS], nzp[RROWS];
    float rmin[RROWS];
    #pragma unroll
    for (int r = 0; r < RROWS; ++r) {
        int i = qbase + r * BLOCK + t;
        const v4f A  = ((const v4f*)qry)[(i >> 1) * 2 + 0];  // [x0 x1 y0 y1]
        const v4f Bq = ((const v4f*)qry)[(i >> 1) * 2 + 1];  // [z0 z1 w0 w1]
        float x = (i & 1) ? A[1] : A[0];
        float y = (i & 1) ? A[3] : A[2];
        float z = (i & 1) ? Bq[1] : Bq[0];
        nxp[r] = (v2f){-2.0f * x, -2.0f * x};
        nyp[r] = (v2f){-2.0f * y, -2.0f * y};
        nzp[r] = (v2f){-2.0f * z, -2.0f * z};
        rmin[r] = INFINITY;
    }

    const int mc = MM / SPLIT;             // 128 targets = 64 pairs per block
    const v4f* __restrict__ tp4 =
        (const v4f*)(tgt + (size_t)b * MM + (size_t)blockIdx.y * mc);

    #pragma unroll 4
    for (int jp = 0; jp < mc / 2; ++jp) {
        v4f A  = tp4[jp * 2 + 0];          // x0 x1 y0 y1
        v4f Bt = tp4[jp * 2 + 1];          // z0 z1 w0 w1
        v2f xx = __builtin_shufflevector(A, A, 0, 1);
        v2f yy = __builtin_shufflevector(A, A, 2, 3);
        v2f zz = __builtin_shufflevector(Bt, Bt, 0, 1);
        v2f ww = __builtin_shufflevector(Bt, Bt, 2, 3);
        #pragma unroll
        for (int r = 0; r < RROWS; ++r) {
            v2f acc;
            asm("v_pk_fma_f32 %0, %1, %2, %3"
                : "=v"(acc) : "v"(nxp[r]), "v"(xx), "v"(ww));
            asm("v_pk_fma_f32 %0, %1, %2, %0"
                : "+v"(acc) : "v"(nyp[r]), "v"(yy));
            asm("v_pk_fma_f32 %0, %1, %2, %0"
                : "+v"(acc) : "v"(nzp[r]), "v"(zz));
            rmin[r] = fminf(rmin[r], fminf(acc[0], acc[1]));  // v_min3_f32
        }
    }

    #pragma unroll
    for (int r = 0; r < RROWS; ++r)
        atomicMin(&okeys[qbase + r * BLOCK + t], enc_key(rmin[r]));
}

// 8 slice-blocks per batch; partial sums atomicAdd'ed into out[b].
#define FSLICE 8
__global__ __launch_bounds__(BLOCK) void chamfer_finalize(
        const int* __restrict__ rk, const int* __restrict__ ck,
        const float4* __restrict__ pp, const float4* __restrict__ pt,
        float* __restrict__ out) {
    const int b = blockIdx.x / FSLICE;
    const int s = blockIdx.x % FSLICE;
    const int t = threadIdx.x;
    const int span = NN / FSLICE;          // 1024
    const float* ppf = (const float*)pp;
    const float* ptf = (const float*)pt;
    float sA = 0.0f, sB = 0.0f;
    for (int n = s * span + t; n < (s + 1) * span; n += BLOCK) {
        int i = b * NN + n;
        float w = ppf[(size_t)(i >> 1) * 8 + 6 + (i & 1)];
        float d2 = w + dec_key(rk[i]);
        sA += sqrtf(fmaxf(d2, 0.0f));
    }
    for (int m = s * span + t; m < (s + 1) * span; m += BLOCK) {
        int i = b * MM + m;
        float w = ptf[(size_t)(i >> 1) * 8 + 6 + (i & 1)];
        float d2 = w + dec_key(ck[i]);
        sB += sqrtf(fmaxf(d2, 0.0f));
    }
    __shared__ float red[BLOCK];
    red[t] = 0.5f * (sA / (float)NN + sB / (float)MM);
    __syncthreads();
    for (int off = BLOCK / 2; off > 0; off >>= 1) {
        if (t < off) red[t] += red[t + off];
        __syncthreads();
    }
    if (t == 0) atomicAdd(&out[b], red[0]);
}

extern "C" void kernel_launch(void* const* d_in, const int* in_sizes, int n_in,
                              void* d_out, int out_size, void* d_ws, size_t ws_size,
                              hipStream_t stream) {
    const float* pred = (const float*)d_in[0];
    const float* tgtp = (const float*)d_in[1];
    float* out = (float*)d_out;

    // ws layout: packed pred (1 MB) | packed tgt (1 MB) | row keys (256 KB) |
    // col keys (256 KB). Total 2.5 MB.
    char* ws = (char*)d_ws;
    float4* pp = (float4*)ws;
    float4* pt = (float4*)(ws + (size_t)BN * sizeof(float4));
    int* rk = (int*)(ws + (size_t)(BN + BM) * sizeof(float4));
    int* ck = rk + BN;

    chamfer_pack<<<NPAIR / BLOCK, BLOCK, 0, stream>>>(pred, tgtp, pp, pt, rk, ck, out);

    // 32 q-blocks x 64 m-chunks x 2 dirs = 4096 blocks = 16 blocks/CU.
    chamfer_minpass<<<dim3(BN / QB, SPLIT, 2), BLOCK, 0, stream>>>(pp, pt, rk, ck);

    chamfer_finalize<<<BB * FSLICE, BLOCK, 0, stream>>>(rk, ck, pp, pt, out);
}